// Round 13
// baseline (464.993 us; speedup 1.0000x reference)
//
#include <hip/hip_runtime.h>
#include <hip/hip_fp16.h>

#define NN 100000
#define NE 1600000
#define FDIM 128
#define NACT 8
#define NG 1024

#define EBLK 4096                        // edges per binning block
#define NBLK4 ((NE + EBLK - 1) / EBLK)   // 391
#define NBKT ((NN + 255) / 256)          // 391 buckets of 256 nodes
#define NSCAN (NBKT * NBLK4)             // 152881
#define NBSC ((NSCAN + 1023) / 1024)     // 150

typedef __attribute__((ext_vector_type(8))) _Float16 half8;
typedef __attribute__((ext_vector_type(4))) float floatx4;

// ---------------------------------------------------------------- binning

__global__ __launch_bounds__(256) void bin_hist(const int* __restrict__ src,
                                                const int* __restrict__ dst,
                                                int* __restrict__ gh) {
    __shared__ int hist[NBKT];
    for (int i = threadIdx.x; i < NBKT; i += 256) hist[i] = 0;
    __syncthreads();
    const int base = blockIdx.x * EBLK + threadIdx.x;
#pragma unroll
    for (int j = 0; j < 16; ++j) {
        int e = base + j * 256;
        if (e < NE) {
            int d = dst[e], s = src[e];
            if (d >= 0 && d < NN && s >= 0 && s < NN) atomicAdd(&hist[d >> 8], 1);
        }
    }
    __syncthreads();
    for (int i = threadIdx.x; i < NBKT; i += 256)
        gh[i * NBLK4 + blockIdx.x] = hist[i];
}

__global__ __launch_bounds__(256) void gscan_bsum(const int* __restrict__ a,
                                                  int* __restrict__ part, int n) {
    __shared__ int s[256];
    int base = blockIdx.x * 1024 + threadIdx.x * 4;
    int tot = 0;
#pragma unroll
    for (int j = 0; j < 4; ++j) {
        int i = base + j;
        tot += (i < n) ? a[i] : 0;
    }
    s[threadIdx.x] = tot;
    __syncthreads();
    for (int off = 128; off > 0; off >>= 1) {
        if (threadIdx.x < off) s[threadIdx.x] += s[threadIdx.x + off];
        __syncthreads();
    }
    if (threadIdx.x == 0) part[blockIdx.x] = s[0];
}

__global__ void scan_part(int* __restrict__ part, int nb) {
    if (blockIdx.x == 0 && threadIdx.x == 0) {
        int run = 0;
        for (int i = 0; i < nb; ++i) {
            int v = part[i];
            part[i] = run;
            run += v;
        }
    }
}

__global__ __launch_bounds__(256) void gscan_write(const int* __restrict__ a,
                                                   const int* __restrict__ part,
                                                   int* __restrict__ outp, int n) {
    __shared__ int s[256];
    const int tid = threadIdx.x;
    int base = blockIdx.x * 1024 + tid * 4;
    int d[4];
    int tot = 0;
#pragma unroll
    for (int j = 0; j < 4; ++j) {
        int i = base + j;
        d[j] = (i < n) ? a[i] : 0;
        tot += d[j];
    }
    s[tid] = tot;
    __syncthreads();
    for (int off = 1; off < 256; off <<= 1) {
        int v = (tid >= off) ? s[tid - off] : 0;
        __syncthreads();
        s[tid] += v;
        __syncthreads();
    }
    int run = part[blockIdx.x] + s[tid] - tot;
#pragma unroll
    for (int j = 0; j < 4; ++j) {
        int i = base + j;
        if (i < n) {
            outp[i] = run;
            run += d[j];
        }
    }
}

__global__ __launch_bounds__(256) void bin_write(const int* __restrict__ src,
                                                 const int* __restrict__ dst,
                                                 const int* __restrict__ ghs,
                                                 unsigned* __restrict__ binned) {
    __shared__ int ofs[NBKT];
    for (int i = threadIdx.x; i < NBKT; i += 256)
        ofs[i] = ghs[i * NBLK4 + blockIdx.x];
    __syncthreads();
    const int base = blockIdx.x * EBLK + threadIdx.x;
#pragma unroll
    for (int j = 0; j < 16; ++j) {
        int e = base + j * 256;
        if (e < NE) {
            int d = dst[e], s = src[e];
            if (d >= 0 && d < NN && s >= 0 && s < NN) {
                int pos = atomicAdd(&ofs[d >> 8], 1);
                if (pos >= 0 && pos < NE)
                    binned[pos] = ((unsigned)s << 8) | (unsigned)(d & 255);
            }
        }
    }
}

// ---------------------------------------------------------------- bucket CSR
__global__ __launch_bounds__(256) void csr_build_bucket(const unsigned* __restrict__ binned,
                                                        const int* __restrict__ ghs,
                                                        int* __restrict__ rp,
                                                        float* __restrict__ dinv,
                                                        int* __restrict__ csr) {
    const int b = blockIdx.x;
    const int tid = threadIdx.x;
    const int bstart = ghs[b * NBLK4];
    const int bend = (b < NBKT - 1) ? ghs[(b + 1) * NBLK4] : NE;
    __shared__ int cnt[256];
    __shared__ int scn[256];
    __shared__ int cur[256];
    cnt[tid] = 0;
    __syncthreads();

    for (int e = bstart + tid; e < bend; e += 256)
        atomicAdd(&cnt[binned[e] & 255u], 1);
    __syncthreads();

    const int myc = cnt[tid];
    scn[tid] = myc;
    __syncthreads();
    for (int off = 1; off < 256; off <<= 1) {
        int v = (tid >= off) ? scn[tid - off] : 0;
        __syncthreads();
        scn[tid] += v;
        __syncthreads();
    }
    const int excl = scn[tid] - myc;
    cur[tid] = bstart + excl;
    const int node = b * 256 + tid;
    if (node < NN) {
        rp[node] = bstart + excl;
        dinv[node] = rsqrtf((float)(myc + 1));  // +1 self-loop
    } else if (node == NN) {
        rp[NN] = bstart + excl;
    }
    __syncthreads();

    for (int e = bstart + tid; e < bend; e += 256) {
        const unsigned v = binned[e];
        const int pos = atomicAdd(&cur[v & 255u], 1);
        if (pos >= 0 && pos < NE) csr[pos] = (int)(v >> 8);
    }
}

// ---------------------------------------------------------------- W -> Wt fp16
__global__ __launch_bounds__(256) void prep_wt(const float* __restrict__ W1,
                                               const float* __restrict__ W2,
                                               const float* __restrict__ W3,
                                               __half* __restrict__ wt) {
    int i = blockIdx.x * 256 + threadIdx.x;
    if (i >= 3 * FDIM * FDIM) return;
    int m = i >> 14;
    int c = (i >> 7) & 127;
    int k = i & 127;
    const float* W = (m == 0) ? W1 : (m == 1) ? W2 : W3;
    wt[(m << 14) + (c << 7) + k] = __float2half(W[(k << 7) + c]);
}

// ---------------------------------------------------------------- GEMM (MFMA)
template <typename AT>
__global__ __launch_bounds__(256) void gemm_mfma(const AT* __restrict__ A,
                                                 const __half* __restrict__ wt,
                                                 __half* __restrict__ C, int M) {
    __shared__ __half Cs[64 * 136];  // 17 KB
    const int tid = threadIdx.x;
    const int wid = tid >> 6;
    const int lane = tid & 63;
    const int l15 = lane & 15;
    const int lk = lane >> 4;  // 0..3
    const int row0 = blockIdx.x * 64 + wid * 16;

    const int arow = min(row0 + l15, M - 1);
    const AT* Ar = A + (size_t)arow * FDIM;

    half8 afr[4];
#pragma unroll
    for (int kb = 0; kb < 4; ++kb) {
        if constexpr (sizeof(AT) == 4) {
            const float4 f0 = *(const float4*)((const float*)Ar + kb * 32 + lk * 8);
            const float4 f1 = *(const float4*)((const float*)Ar + kb * 32 + lk * 8 + 4);
            half8 h;
            h[0] = (_Float16)f0.x; h[1] = (_Float16)f0.y;
            h[2] = (_Float16)f0.z; h[3] = (_Float16)f0.w;
            h[4] = (_Float16)f1.x; h[5] = (_Float16)f1.y;
            h[6] = (_Float16)f1.z; h[7] = (_Float16)f1.w;
            afr[kb] = h;
        } else {
            afr[kb] = *(const half8*)((const __half*)Ar + kb * 32 + lk * 8);
        }
    }

    floatx4 acc[8];
#pragma unroll
    for (int ct = 0; ct < 8; ++ct) acc[ct] = (floatx4){0.f, 0.f, 0.f, 0.f};

#pragma unroll
    for (int ct = 0; ct < 8; ++ct) {
#pragma unroll
        for (int kb = 0; kb < 4; ++kb) {
            const half8 b = *(const half8*)(wt + (ct * 16 + l15) * FDIM + kb * 32 + lk * 8);
            acc[ct] = __builtin_amdgcn_mfma_f32_16x16x32_f16(afr[kb], b, acc[ct], 0, 0, 0);
        }
    }

#pragma unroll
    for (int ct = 0; ct < 8; ++ct) {
#pragma unroll
        for (int r = 0; r < 4; ++r) {
            Cs[(wid * 16 + lk * 4 + r) * 136 + ct * 16 + l15] = __float2half(acc[ct][r]);
        }
    }
    __syncthreads();

#pragma unroll
    for (int j = 0; j < 4; ++j) {
        const int idx = tid + j * 256;
        const int rb = idx >> 4;
        const int cq = idx & 15;
        const int row = blockIdx.x * 64 + rb;
        if (row < M) {
            const uint4 v = *(const uint4*)(Cs + rb * 136 + cq * 8);
            *(uint4*)(C + (size_t)row * FDIM + cq * 8) = v;
        }
    }
}

// ---------------------------------------------------------------- aggregation
// 16 lanes/node, uint4 (8 halves)/lane; edge loop unrolled x8 -> 8 gathers
// in flight per node-group (32/wave). fp32 accumulate, fp16 out.
__device__ inline void unpack8(uint4 u, float f[8]) {
    __half2 a = *(__half2*)&u.x;
    __half2 b = *(__half2*)&u.y;
    __half2 c = *(__half2*)&u.z;
    __half2 d = *(__half2*)&u.w;
    float2 fa = __half22float2(a), fb = __half22float2(b);
    float2 fc = __half22float2(c), fd = __half22float2(d);
    f[0] = fa.x; f[1] = fa.y; f[2] = fb.x; f[3] = fb.y;
    f[4] = fc.x; f[5] = fc.y; f[6] = fd.x; f[7] = fd.y;
}

__global__ __launch_bounds__(256) void gcn_agg(const __half* __restrict__ h,
                                               const int* __restrict__ csr,
                                               const int* __restrict__ rp,
                                               const float* __restrict__ dinv,
                                               const float* __restrict__ bias,
                                               __half* __restrict__ out) {
    const int node = blockIdx.x * 16 + (threadIdx.x >> 4);
    const int fg = threadIdx.x & 15;
    const uint4* __restrict__ h16 = (const uint4*)h;

    const float di = dinv[node];
    const float sw = di * di;
    float acc[8];
    {
        float a[8];
        unpack8(h16[(size_t)node * 16 + fg], a);
#pragma unroll
        for (int j = 0; j < 8; ++j) acc[j] = a[j] * sw;
    }

    int e0 = rp[node], e1 = rp[node + 1];
    if (e0 < 0) e0 = 0;
    if (e1 > NE) e1 = NE;

    int e = e0;
    for (; e + 8 <= e1; e += 8) {
        int s[8];
#pragma unroll
        for (int j = 0; j < 8; ++j)
            s[j] = min((int)(((unsigned)csr[e + j]) & 0x7fffffffu), NN - 1);
        uint4 v[8];
#pragma unroll
        for (int j = 0; j < 8; ++j) v[j] = h16[(size_t)s[j] * 16 + fg];
        float w[8];
#pragma unroll
        for (int j = 0; j < 8; ++j) w[j] = dinv[s[j]] * di;
#pragma unroll
        for (int j = 0; j < 8; ++j) {
            float f[8];
            unpack8(v[j], f);
#pragma unroll
            for (int q = 0; q < 8; ++q) acc[q] = fmaf(w[j], f[q], acc[q]);
        }
    }
    for (; e + 4 <= e1; e += 4) {
        int s[4];
#pragma unroll
        for (int j = 0; j < 4; ++j)
            s[j] = min((int)(((unsigned)csr[e + j]) & 0x7fffffffu), NN - 1);
        uint4 v[4];
#pragma unroll
        for (int j = 0; j < 4; ++j) v[j] = h16[(size_t)s[j] * 16 + fg];
        float w[4];
#pragma unroll
        for (int j = 0; j < 4; ++j) w[j] = dinv[s[j]] * di;
#pragma unroll
        for (int j = 0; j < 4; ++j) {
            float f[8];
            unpack8(v[j], f);
#pragma unroll
            for (int q = 0; q < 8; ++q) acc[q] = fmaf(w[j], f[q], acc[q]);
        }
    }
    for (; e < e1; ++e) {
        const int s = min((int)(((unsigned)csr[e]) & 0x7fffffffu), NN - 1);
        const float w = dinv[s] * di;
        float f[8];
        unpack8(h16[(size_t)s * 16 + fg], f);
#pragma unroll
        for (int q = 0; q < 8; ++q) acc[q] = fmaf(w, f[q], acc[q]);
    }

    const float4 b0 = ((const float4*)bias)[fg * 2];
    const float4 b1 = ((const float4*)bias)[fg * 2 + 1];
    float o[8];
    o[0] = fmaxf(acc[0] + b0.x, 0.f); o[1] = fmaxf(acc[1] + b0.y, 0.f);
    o[2] = fmaxf(acc[2] + b0.z, 0.f); o[3] = fmaxf(acc[3] + b0.w, 0.f);
    o[4] = fmaxf(acc[4] + b1.x, 0.f); o[5] = fmaxf(acc[5] + b1.y, 0.f);
    o[6] = fmaxf(acc[6] + b1.z, 0.f); o[7] = fmaxf(acc[7] + b1.w, 0.f);
    __half2 p0 = __floats2half2_rn(o[0], o[1]);
    __half2 p1 = __floats2half2_rn(o[2], o[3]);
    __half2 p2 = __floats2half2_rn(o[4], o[5]);
    __half2 p3 = __floats2half2_rn(o[6], o[7]);
    uint4 pk;
    pk.x = *(unsigned*)&p0; pk.y = *(unsigned*)&p1;
    pk.z = *(unsigned*)&p2; pk.w = *(unsigned*)&p3;
    ((uint4*)out)[(size_t)node * 16 + fg] = pk;
}

// ---------------------------------------------------------------- head + pool
__global__ __launch_bounds__(256) void head_pool(const __half* __restrict__ h,
                                                 const float* __restrict__ Wl,
                                                 const float* __restrict__ bl,
                                                 const int* __restrict__ batch,
                                                 float* __restrict__ out) {
    const int g = blockIdx.x;
    const int tid = threadIdx.x;

    int lo = 0, hi = NN;
    while (lo < hi) {
        int mid = (lo + hi) >> 1;
        if (batch[mid] < g) lo = mid + 1; else hi = mid;
    }
    const int start = lo;
    hi = NN;
    while (lo < hi) {
        int mid = (lo + hi) >> 1;
        if (batch[mid] <= g) lo = mid + 1; else hi = mid;
    }
    const int end = lo;

    __shared__ float Ws[FDIM * NACT];
    for (int i = tid; i < FDIM * NACT; i += 256) Ws[i] = Wl[i];
    __syncthreads();

    float acc[NACT];
#pragma unroll
    for (int f = 0; f < NACT; ++f) acc[f] = 0.f;

    for (int v = start + tid; v < end; v += 256) {
        float o[NACT];
#pragma unroll
        for (int f = 0; f < NACT; ++f) o[f] = bl[f];
        const uint4* h16 = (const uint4*)h + (size_t)v * 16;
        for (int k8 = 0; k8 < 16; ++k8) {
            float xf[8];
            unpack8(h16[k8], xf);
#pragma unroll
            for (int j = 0; j < 8; ++j) {
#pragma unroll
                for (int f = 0; f < NACT; ++f)
                    o[f] = fmaf(xf[j], Ws[(k8 * 8 + j) * NACT + f], o[f]);
            }
        }
#pragma unroll
        for (int f = 0; f < NACT; ++f) acc[f] += tanhf(o[f]);
    }

    __shared__ float red[256 * NACT];
#pragma unroll
    for (int f = 0; f < NACT; ++f) red[tid * NACT + f] = acc[f];
    __syncthreads();
    for (int off = 128; off > 0; off >>= 1) {
        if (tid < off) {
#pragma unroll
            for (int f = 0; f < NACT; ++f)
                red[tid * NACT + f] += red[(tid + off) * NACT + f];
        }
        __syncthreads();
    }
    if (tid < NACT) {
        const float inv = 1.0f / fmaxf((float)(end - start), 1.0f);
        out[g * NACT + tid] = red[tid] * inv;
    }
}

// ---------------------------------------------------------------- launch

extern "C" void kernel_launch(void* const* d_in, const int* in_sizes, int n_in,
                              void* d_out, int out_size, void* d_ws, size_t ws_size,
                              hipStream_t stream) {
    const float* x = (const float*)d_in[0];
    const int* ei = (const int*)d_in[1];
    const int* batch = (const int*)d_in[2];
    const float* W1 = (const float*)d_in[3];
    const float* b1 = (const float*)d_in[4];
    const float* W2 = (const float*)d_in[5];
    const float* b2 = (const float*)d_in[6];
    const float* W3 = (const float*)d_in[7];
    const float* b3 = (const float*)d_in[8];
    const float* Wl = (const float*)d_in[9];
    const float* bl = (const float*)d_in[10];

    const int* src = ei;
    const int* dst = ei + NE;

    char* p = (char*)d_ws;
    auto alloc = [&](size_t bytes) {
        void* r = (void*)p;
        p += (bytes + 255) & ~(size_t)255;
        return r;
    };
    __half* hbuf    = (__half*)alloc((size_t)NN * FDIM * 2);  // 25.6 MB (gemm out)
    __half* abuf    = (__half*)alloc((size_t)NN * FDIM * 2);  // 25.6 MB (agg out)
    int* csr        = (int*)alloc((size_t)NE * 4);            // 6.4 MB
    unsigned* binned= (unsigned*)alloc((size_t)NE * 4);       // 6.4 MB
    int* gh         = (int*)alloc((size_t)NSCAN * 4);         // 612 KB
    int* ghs        = (int*)alloc((size_t)NSCAN * 4);         // 612 KB
    __half* wt      = (__half*)alloc(3 * FDIM * FDIM * 2);    // 96 KB
    int* rp         = (int*)alloc((NN + 1) * 4);
    float* dinv     = (float*)alloc(NN * 4);
    int* part2      = (int*)alloc(4096);

    prep_wt<<<(3 * FDIM * FDIM + 255) / 256, 256, 0, stream>>>(W1, W2, W3, wt);
    bin_hist<<<NBLK4, 256, 0, stream>>>(src, dst, gh);
    gscan_bsum<<<NBSC, 256, 0, stream>>>(gh, part2, NSCAN);
    scan_part<<<1, 64, 0, stream>>>(part2, NBSC);
    gscan_write<<<NBSC, 256, 0, stream>>>(gh, part2, ghs, NSCAN);
    bin_write<<<NBLK4, 256, 0, stream>>>(src, dst, ghs, binned);
    csr_build_bucket<<<NBKT, 256, 0, stream>>>(binned, ghs, rp, dinv, csr);

    const int GB = (NN + 63) / 64;   // 1563
    const int AB = NN / 16;          // 6250
    gemm_mfma<float><<<GB, 256, 0, stream>>>(x, wt, hbuf, NN);
    gcn_agg<<<AB, 256, 0, stream>>>(hbuf, csr, rp, dinv, b1, abuf);
    gemm_mfma<__half><<<GB, 256, 0, stream>>>(abuf, wt + FDIM * FDIM, hbuf, NN);
    gcn_agg<<<AB, 256, 0, stream>>>(hbuf, csr, rp, dinv, b2, abuf);
    gemm_mfma<__half><<<GB, 256, 0, stream>>>(abuf, wt + 2 * FDIM * FDIM, hbuf, NN);
    gcn_agg<<<AB, 256, 0, stream>>>(hbuf, csr, rp, dinv, b3, abuf);

    head_pool<<<NG, 256, 0, stream>>>(abuf, Wl, bl, batch, (float*)d_out);
}

// Round 14
// 440.051 us; speedup vs baseline: 1.0567x; 1.0567x over previous
//
#include <hip/hip_runtime.h>
#include <hip/hip_fp16.h>

#define NN 100000
#define NE 1600000
#define FDIM 128
#define NACT 8
#define NG 1024

#define EBLK 4096                        // edges per binning block
#define NBLK4 ((NE + EBLK - 1) / EBLK)   // 391
#define NBKT ((NN + 255) / 256)          // 391 buckets of 256 nodes
#define NSCAN (NBKT * NBLK4)             // 152881
#define NBSC ((NSCAN + 1023) / 1024)     // 150

typedef __attribute__((ext_vector_type(8))) _Float16 half8;
typedef __attribute__((ext_vector_type(4))) float floatx4;

// ---------------------------------------------------------------- binning

__global__ __launch_bounds__(256) void bin_hist(const int* __restrict__ src,
                                                const int* __restrict__ dst,
                                                int* __restrict__ gh) {
    __shared__ int hist[NBKT];
    for (int i = threadIdx.x; i < NBKT; i += 256) hist[i] = 0;
    __syncthreads();
    const int base = blockIdx.x * EBLK + threadIdx.x;
#pragma unroll
    for (int j = 0; j < 16; ++j) {
        int e = base + j * 256;
        if (e < NE) {
            int d = dst[e], s = src[e];
            if (d >= 0 && d < NN && s >= 0 && s < NN) atomicAdd(&hist[d >> 8], 1);
        }
    }
    __syncthreads();
    for (int i = threadIdx.x; i < NBKT; i += 256)
        gh[i * NBLK4 + blockIdx.x] = hist[i];
}

__global__ __launch_bounds__(256) void gscan_bsum(const int* __restrict__ a,
                                                  int* __restrict__ part, int n) {
    __shared__ int s[256];
    int base = blockIdx.x * 1024 + threadIdx.x * 4;
    int tot = 0;
#pragma unroll
    for (int j = 0; j < 4; ++j) {
        int i = base + j;
        tot += (i < n) ? a[i] : 0;
    }
    s[threadIdx.x] = tot;
    __syncthreads();
    for (int off = 128; off > 0; off >>= 1) {
        if (threadIdx.x < off) s[threadIdx.x] += s[threadIdx.x + off];
        __syncthreads();
    }
    if (threadIdx.x == 0) part[blockIdx.x] = s[0];
}

// parallel exclusive scan of the block partials (was a single-thread serial
// loop over 150 entries = hidden serial-latency chain; now ~2 us).
__global__ __launch_bounds__(256) void scan_part_par(int* __restrict__ part, int nb) {
    __shared__ int s[256];
    const int tid = threadIdx.x;
    const int v = (tid < nb) ? part[tid] : 0;
    s[tid] = v;
    __syncthreads();
    for (int off = 1; off < 256; off <<= 1) {
        int u = (tid >= off) ? s[tid - off] : 0;
        __syncthreads();
        s[tid] += u;
        __syncthreads();
    }
    if (tid < nb) part[tid] = s[tid] - v;
}

__global__ __launch_bounds__(256) void gscan_write(const int* __restrict__ a,
                                                   const int* __restrict__ part,
                                                   int* __restrict__ outp, int n) {
    __shared__ int s[256];
    const int tid = threadIdx.x;
    int base = blockIdx.x * 1024 + tid * 4;
    int d[4];
    int tot = 0;
#pragma unroll
    for (int j = 0; j < 4; ++j) {
        int i = base + j;
        d[j] = (i < n) ? a[i] : 0;
        tot += d[j];
    }
    s[tid] = tot;
    __syncthreads();
    for (int off = 1; off < 256; off <<= 1) {
        int v = (tid >= off) ? s[tid - off] : 0;
        __syncthreads();
        s[tid] += v;
        __syncthreads();
    }
    int run = part[blockIdx.x] + s[tid] - tot;
#pragma unroll
    for (int j = 0; j < 4; ++j) {
        int i = base + j;
        if (i < n) {
            outp[i] = run;
            run += d[j];
        }
    }
}

__global__ __launch_bounds__(256) void bin_write(const int* __restrict__ src,
                                                 const int* __restrict__ dst,
                                                 const int* __restrict__ ghs,
                                                 unsigned* __restrict__ binned) {
    __shared__ int ofs[NBKT];
    for (int i = threadIdx.x; i < NBKT; i += 256)
        ofs[i] = ghs[i * NBLK4 + blockIdx.x];
    __syncthreads();
    const int base = blockIdx.x * EBLK + threadIdx.x;
#pragma unroll
    for (int j = 0; j < 16; ++j) {
        int e = base + j * 256;
        if (e < NE) {
            int d = dst[e], s = src[e];
            if (d >= 0 && d < NN && s >= 0 && s < NN) {
                int pos = atomicAdd(&ofs[d >> 8], 1);
                if (pos >= 0 && pos < NE)
                    binned[pos] = ((unsigned)s << 8) | (unsigned)(d & 255);
            }
        }
    }
}

// ---------------------------------------------------------------- bucket CSR
__global__ __launch_bounds__(256) void csr_build_bucket(const unsigned* __restrict__ binned,
                                                        const int* __restrict__ ghs,
                                                        int* __restrict__ rp,
                                                        float* __restrict__ dinv,
                                                        int* __restrict__ csr) {
    const int b = blockIdx.x;
    const int tid = threadIdx.x;
    const int bstart = ghs[b * NBLK4];
    const int bend = (b < NBKT - 1) ? ghs[(b + 1) * NBLK4] : NE;
    __shared__ int cnt[256];
    __shared__ int scn[256];
    __shared__ int cur[256];
    cnt[tid] = 0;
    __syncthreads();

    for (int e = bstart + tid; e < bend; e += 256)
        atomicAdd(&cnt[binned[e] & 255u], 1);
    __syncthreads();

    const int myc = cnt[tid];
    scn[tid] = myc;
    __syncthreads();
    for (int off = 1; off < 256; off <<= 1) {
        int v = (tid >= off) ? scn[tid - off] : 0;
        __syncthreads();
        scn[tid] += v;
        __syncthreads();
    }
    const int excl = scn[tid] - myc;
    cur[tid] = bstart + excl;
    const int node = b * 256 + tid;
    if (node < NN) {
        rp[node] = bstart + excl;
        dinv[node] = rsqrtf((float)(myc + 1));  // +1 self-loop
    } else if (node == NN) {
        rp[NN] = bstart + excl;
    }
    __syncthreads();

    for (int e = bstart + tid; e < bend; e += 256) {
        const unsigned v = binned[e];
        const int pos = atomicAdd(&cur[v & 255u], 1);
        if (pos >= 0 && pos < NE) csr[pos] = (int)(v >> 8);
    }
}

// ---------------------------------------------------------------- W -> Wt fp16
__global__ __launch_bounds__(256) void prep_wt(const float* __restrict__ W1,
                                               const float* __restrict__ W2,
                                               const float* __restrict__ W3,
                                               __half* __restrict__ wt) {
    int i = blockIdx.x * 256 + threadIdx.x;
    if (i >= 3 * FDIM * FDIM) return;
    int m = i >> 14;
    int c = (i >> 7) & 127;
    int k = i & 127;
    const float* W = (m == 0) ? W1 : (m == 1) ? W2 : W3;
    wt[(m << 14) + (c << 7) + k] = __float2half(W[(k << 7) + c]);
}

// ---------------------------------------------------------------- GEMM (MFMA)
template <typename AT>
__global__ __launch_bounds__(256) void gemm_mfma(const AT* __restrict__ A,
                                                 const __half* __restrict__ wt,
                                                 __half* __restrict__ C, int M) {
    __shared__ __half Cs[64 * 136];  // 17 KB
    const int tid = threadIdx.x;
    const int wid = tid >> 6;
    const int lane = tid & 63;
    const int l15 = lane & 15;
    const int lk = lane >> 4;  // 0..3
    const int row0 = blockIdx.x * 64 + wid * 16;

    const int arow = min(row0 + l15, M - 1);
    const AT* Ar = A + (size_t)arow * FDIM;

    half8 afr[4];
#pragma unroll
    for (int kb = 0; kb < 4; ++kb) {
        if constexpr (sizeof(AT) == 4) {
            const float4 f0 = *(const float4*)((const float*)Ar + kb * 32 + lk * 8);
            const float4 f1 = *(const float4*)((const float*)Ar + kb * 32 + lk * 8 + 4);
            half8 h;
            h[0] = (_Float16)f0.x; h[1] = (_Float16)f0.y;
            h[2] = (_Float16)f0.z; h[3] = (_Float16)f0.w;
            h[4] = (_Float16)f1.x; h[5] = (_Float16)f1.y;
            h[6] = (_Float16)f1.z; h[7] = (_Float16)f1.w;
            afr[kb] = h;
        } else {
            afr[kb] = *(const half8*)((const __half*)Ar + kb * 32 + lk * 8);
        }
    }

    floatx4 acc[8];
#pragma unroll
    for (int ct = 0; ct < 8; ++ct) acc[ct] = (floatx4){0.f, 0.f, 0.f, 0.f};

#pragma unroll
    for (int ct = 0; ct < 8; ++ct) {
#pragma unroll
        for (int kb = 0; kb < 4; ++kb) {
            const half8 b = *(const half8*)(wt + (ct * 16 + l15) * FDIM + kb * 32 + lk * 8);
            acc[ct] = __builtin_amdgcn_mfma_f32_16x16x32_f16(afr[kb], b, acc[ct], 0, 0, 0);
        }
    }

#pragma unroll
    for (int ct = 0; ct < 8; ++ct) {
#pragma unroll
        for (int r = 0; r < 4; ++r) {
            Cs[(wid * 16 + lk * 4 + r) * 136 + ct * 16 + l15] = __float2half(acc[ct][r]);
        }
    }
    __syncthreads();

#pragma unroll
    for (int j = 0; j < 4; ++j) {
        const int idx = tid + j * 256;
        const int rb = idx >> 4;
        const int cq = idx & 15;
        const int row = blockIdx.x * 64 + rb;
        if (row < M) {
            const uint4 v = *(const uint4*)(Cs + rb * 136 + cq * 8);
            *(uint4*)(C + (size_t)row * FDIM + cq * 8) = v;
        }
    }
}

// ---------------------------------------------------------------- aggregation
// 16 lanes/node, uint4 (8 halves)/lane; x4 unroll (x8 regressed in R13:
// 61.4->64.4 us, occupancy 71->60% -- gather path saturates at ~3.7 TB/s).
__device__ inline void unpack8(uint4 u, float f[8]) {
    __half2 a = *(__half2*)&u.x;
    __half2 b = *(__half2*)&u.y;
    __half2 c = *(__half2*)&u.z;
    __half2 d = *(__half2*)&u.w;
    float2 fa = __half22float2(a), fb = __half22float2(b);
    float2 fc = __half22float2(c), fd = __half22float2(d);
    f[0] = fa.x; f[1] = fa.y; f[2] = fb.x; f[3] = fb.y;
    f[4] = fc.x; f[5] = fc.y; f[6] = fd.x; f[7] = fd.y;
}

__global__ __launch_bounds__(256) void gcn_agg(const __half* __restrict__ h,
                                               const int* __restrict__ csr,
                                               const int* __restrict__ rp,
                                               const float* __restrict__ dinv,
                                               const float* __restrict__ bias,
                                               __half* __restrict__ out) {
    const int node = blockIdx.x * 16 + (threadIdx.x >> 4);
    const int fg = threadIdx.x & 15;
    const uint4* __restrict__ h16 = (const uint4*)h;

    const float di = dinv[node];
    const float sw = di * di;
    float acc[8];
    {
        float a[8];
        unpack8(h16[(size_t)node * 16 + fg], a);
#pragma unroll
        for (int j = 0; j < 8; ++j) acc[j] = a[j] * sw;
    }

    int e0 = rp[node], e1 = rp[node + 1];
    if (e0 < 0) e0 = 0;
    if (e1 > NE) e1 = NE;

    int e = e0;
    for (; e + 4 <= e1; e += 4) {
        const int s0 = min((int)(((unsigned)csr[e + 0]) & 0x7fffffffu), NN - 1);
        const int s1 = min((int)(((unsigned)csr[e + 1]) & 0x7fffffffu), NN - 1);
        const int s2 = min((int)(((unsigned)csr[e + 2]) & 0x7fffffffu), NN - 1);
        const int s3 = min((int)(((unsigned)csr[e + 3]) & 0x7fffffffu), NN - 1);
        const uint4 v0 = h16[(size_t)s0 * 16 + fg];
        const uint4 v1 = h16[(size_t)s1 * 16 + fg];
        const uint4 v2 = h16[(size_t)s2 * 16 + fg];
        const uint4 v3 = h16[(size_t)s3 * 16 + fg];
        const float w0 = dinv[s0] * di;
        const float w1 = dinv[s1] * di;
        const float w2 = dinv[s2] * di;
        const float w3 = dinv[s3] * di;
        float f0[8], f1[8], f2[8], f3[8];
        unpack8(v0, f0); unpack8(v1, f1); unpack8(v2, f2); unpack8(v3, f3);
#pragma unroll
        for (int j = 0; j < 8; ++j) acc[j] = fmaf(w0, f0[j], acc[j]);
#pragma unroll
        for (int j = 0; j < 8; ++j) acc[j] = fmaf(w1, f1[j], acc[j]);
#pragma unroll
        for (int j = 0; j < 8; ++j) acc[j] = fmaf(w2, f2[j], acc[j]);
#pragma unroll
        for (int j = 0; j < 8; ++j) acc[j] = fmaf(w3, f3[j], acc[j]);
    }
    for (; e < e1; ++e) {
        const int s = min((int)(((unsigned)csr[e]) & 0x7fffffffu), NN - 1);
        const float w = dinv[s] * di;
        float f[8];
        unpack8(h16[(size_t)s * 16 + fg], f);
#pragma unroll
        for (int j = 0; j < 8; ++j) acc[j] = fmaf(w, f[j], acc[j]);
    }

    const float4 b0 = ((const float4*)bias)[fg * 2];
    const float4 b1 = ((const float4*)bias)[fg * 2 + 1];
    float o[8];
    o[0] = fmaxf(acc[0] + b0.x, 0.f); o[1] = fmaxf(acc[1] + b0.y, 0.f);
    o[2] = fmaxf(acc[2] + b0.z, 0.f); o[3] = fmaxf(acc[3] + b0.w, 0.f);
    o[4] = fmaxf(acc[4] + b1.x, 0.f); o[5] = fmaxf(acc[5] + b1.y, 0.f);
    o[6] = fmaxf(acc[6] + b1.z, 0.f); o[7] = fmaxf(acc[7] + b1.w, 0.f);
    __half2 p0 = __floats2half2_rn(o[0], o[1]);
    __half2 p1 = __floats2half2_rn(o[2], o[3]);
    __half2 p2 = __floats2half2_rn(o[4], o[5]);
    __half2 p3 = __floats2half2_rn(o[6], o[7]);
    uint4 pk;
    pk.x = *(unsigned*)&p0; pk.y = *(unsigned*)&p1;
    pk.z = *(unsigned*)&p2; pk.w = *(unsigned*)&p3;
    ((uint4*)out)[(size_t)node * 16 + fg] = pk;
}

// ---------------------------------------------------------------- head + pool
__global__ __launch_bounds__(256) void head_pool(const __half* __restrict__ h,
                                                 const float* __restrict__ Wl,
                                                 const float* __restrict__ bl,
                                                 const int* __restrict__ batch,
                                                 float* __restrict__ out) {
    const int g = blockIdx.x;
    const int tid = threadIdx.x;

    int lo = 0, hi = NN;
    while (lo < hi) {
        int mid = (lo + hi) >> 1;
        if (batch[mid] < g) lo = mid + 1; else hi = mid;
    }
    const int start = lo;
    hi = NN;
    while (lo < hi) {
        int mid = (lo + hi) >> 1;
        if (batch[mid] <= g) lo = mid + 1; else hi = mid;
    }
    const int end = lo;

    __shared__ float Ws[FDIM * NACT];
    for (int i = tid; i < FDIM * NACT; i += 256) Ws[i] = Wl[i];
    __syncthreads();

    float acc[NACT];
#pragma unroll
    for (int f = 0; f < NACT; ++f) acc[f] = 0.f;

    for (int v = start + tid; v < end; v += 256) {
        float o[NACT];
#pragma unroll
        for (int f = 0; f < NACT; ++f) o[f] = bl[f];
        const uint4* h16 = (const uint4*)h + (size_t)v * 16;
        for (int k8 = 0; k8 < 16; ++k8) {
            float xf[8];
            unpack8(h16[k8], xf);
#pragma unroll
            for (int j = 0; j < 8; ++j) {
#pragma unroll
                for (int f = 0; f < NACT; ++f)
                    o[f] = fmaf(xf[j], Ws[(k8 * 8 + j) * NACT + f], o[f]);
            }
        }
#pragma unroll
        for (int f = 0; f < NACT; ++f) acc[f] += tanhf(o[f]);
    }

    __shared__ float red[256 * NACT];
#pragma unroll
    for (int f = 0; f < NACT; ++f) red[tid * NACT + f] = acc[f];
    __syncthreads();
    for (int off = 128; off > 0; off >>= 1) {
        if (tid < off) {
#pragma unroll
            for (int f = 0; f < NACT; ++f)
                red[tid * NACT + f] += red[(tid + off) * NACT + f];
        }
        __syncthreads();
    }
    if (tid < NACT) {
        const float inv = 1.0f / fmaxf((float)(end - start), 1.0f);
        out[g * NACT + tid] = red[tid] * inv;
    }
}

// ---------------------------------------------------------------- launch

extern "C" void kernel_launch(void* const* d_in, const int* in_sizes, int n_in,
                              void* d_out, int out_size, void* d_ws, size_t ws_size,
                              hipStream_t stream) {
    const float* x = (const float*)d_in[0];
    const int* ei = (const int*)d_in[1];
    const int* batch = (const int*)d_in[2];
    const float* W1 = (const float*)d_in[3];
    const float* b1 = (const float*)d_in[4];
    const float* W2 = (const float*)d_in[5];
    const float* b2 = (const float*)d_in[6];
    const float* W3 = (const float*)d_in[7];
    const float* b3 = (const float*)d_in[8];
    const float* Wl = (const float*)d_in[9];
    const float* bl = (const float*)d_in[10];

    const int* src = ei;
    const int* dst = ei + NE;

    char* p = (char*)d_ws;
    auto alloc = [&](size_t bytes) {
        void* r = (void*)p;
        p += (bytes + 255) & ~(size_t)255;
        return r;
    };
    __half* hbuf    = (__half*)alloc((size_t)NN * FDIM * 2);  // 25.6 MB (gemm out)
    __half* abuf    = (__half*)alloc((size_t)NN * FDIM * 2);  // 25.6 MB (agg out)
    int* csr        = (int*)alloc((size_t)NE * 4);            // 6.4 MB
    unsigned* binned= (unsigned*)alloc((size_t)NE * 4);       // 6.4 MB
    int* gh         = (int*)alloc((size_t)NSCAN * 4);         // 612 KB
    int* ghs        = (int*)alloc((size_t)NSCAN * 4);         // 612 KB
    __half* wt      = (__half*)alloc(3 * FDIM * FDIM * 2);    // 96 KB
    int* rp         = (int*)alloc((NN + 1) * 4);
    float* dinv     = (float*)alloc(NN * 4);
    int* part2      = (int*)alloc(4096);

    prep_wt<<<(3 * FDIM * FDIM + 255) / 256, 256, 0, stream>>>(W1, W2, W3, wt);
    bin_hist<<<NBLK4, 256, 0, stream>>>(src, dst, gh);
    gscan_bsum<<<NBSC, 256, 0, stream>>>(gh, part2, NSCAN);
    scan_part_par<<<1, 256, 0, stream>>>(part2, NBSC);
    gscan_write<<<NBSC, 256, 0, stream>>>(gh, part2, ghs, NSCAN);
    bin_write<<<NBLK4, 256, 0, stream>>>(src, dst, ghs, binned);
    csr_build_bucket<<<NBKT, 256, 0, stream>>>(binned, ghs, rp, dinv, csr);

    const int GB = (NN + 63) / 64;   // 1563
    const int AB = NN / 16;          // 6250
    gemm_mfma<float><<<GB, 256, 0, stream>>>(x, wt, hbuf, NN);
    gcn_agg<<<AB, 256, 0, stream>>>(hbuf, csr, rp, dinv, b1, abuf);
    gemm_mfma<__half><<<GB, 256, 0, stream>>>(abuf, wt + FDIM * FDIM, hbuf, NN);
    gcn_agg<<<AB, 256, 0, stream>>>(hbuf, csr, rp, dinv, b2, abuf);
    gemm_mfma<__half><<<GB, 256, 0, stream>>>(abuf, wt + 2 * FDIM * FDIM, hbuf, NN);
    gcn_agg<<<AB, 256, 0, stream>>>(hbuf, csr, rp, dinv, b3, abuf);

    head_pool<<<NG, 256, 0, stream>>>(abuf, Wl, bl, batch, (float*)d_out);
}